// Round 1
// baseline (798.217 us; speedup 1.0000x reference)
//
#include <hip/hip_runtime.h>
#include <hip/hip_bf16.h>
#include <math.h>

// Problem constants: B=2, H=W=128, C=256, HEADS=8, D=32, N=16384, M=B*N=32768
typedef short bf16x8 __attribute__((ext_vector_type(8)));
typedef float f32x4 __attribute__((ext_vector_type(4)));

#define MFMA16(a,b,c) __builtin_amdgcn_mfma_f32_16x16x32_bf16(a,b,c,0,0,0)

__device__ inline short f2bf(float f){
  uint32_t u = __builtin_bit_cast(uint32_t, f);
  u += 0x7FFFu + ((u >> 16) & 1u);
  return (short)(u >> 16);
}
__device__ inline float bf2f(short s){
  uint32_t u = ((uint32_t)(uint16_t)s) << 16;
  return __builtin_bit_cast(float, u);
}
__device__ inline void store8bf(short* dst, float4 a, float4 b){
  union{ short s[8]; int4 q; } u;
  u.s[0]=f2bf(a.x); u.s[1]=f2bf(a.y); u.s[2]=f2bf(a.z); u.s[3]=f2bf(a.w);
  u.s[4]=f2bf(b.x); u.s[5]=f2bf(b.y); u.s[6]=f2bf(b.z); u.s[7]=f2bf(b.w);
  *(int4*)dst = u.q;
}

// ---------- generic f32 -> bf16 convert ----------
__global__ __launch_bounds__(256) void k_cvt(const float* __restrict__ src, short* __restrict__ dst, int n){
  int i = blockIdx.x*256 + threadIdx.x;
  if(i < n) dst[i] = f2bf(src[i]);
}

// ---------- transpose-convert the 4 Wv matrices: WvT[br][a][j] = Wv_br[j][a] ----------
__global__ __launch_bounds__(256) void k_wvt(const float* __restrict__ wm, const float* __restrict__ w2,
                                             const float* __restrict__ w4, const float* __restrict__ w8,
                                             short* __restrict__ wvT){
  int t = blockIdx.x*256 + threadIdx.x;      // 4*65536 total
  int br = t >> 16; int rem = t & 65535; int a = rem >> 8, j = rem & 255;
  const float* w = (br==0)? wm : (br==1)? w2 : (br==2)? w4 : w8;
  wvT[t] = f2bf(w[j*256 + a]);
}

// ---------- transpose inputs to XT[sb][c][n] bf16 (sb = src*2+b; src 0=y,1=x2,2=x4,3=x8) ----------
__global__ __launch_bounds__(256) void k_transpose(const float* __restrict__ x2, const float* __restrict__ x4,
                                                   const float* __restrict__ x8, const float* __restrict__ y,
                                                   short* __restrict__ xt){
  int sb = blockIdx.z; int s = sb >> 1, b = sb & 1;
  const float* src = ((s==0)? y : (s==1)? x2 : (s==2)? x4 : x8) + (size_t)b*16384*256;
  __shared__ short tile[64][72];
  int n0 = blockIdx.x*64, c0 = blockIdx.y*64;
  int t = threadIdx.x;
  int nr = t >> 2, cc = (t & 3)*16;
  const float* p = src + (size_t)(n0+nr)*256 + c0 + cc;
  #pragma unroll
  for(int i=0;i<16;i+=4){
    float4 v = *(const float4*)(p + i);
    tile[cc+i  ][nr] = f2bf(v.x); tile[cc+i+1][nr] = f2bf(v.y);
    tile[cc+i+2][nr] = f2bf(v.z); tile[cc+i+3][nr] = f2bf(v.w);
  }
  __syncthreads();
  int cr = t >> 2, nc = (t & 3)*16;
  short* o = xt + ((size_t)sb*256 + c0 + cr)*16384 + n0 + nc;
  ((int4*)o)[0] = *(int4*)&tile[cr][nc];
  ((int4*)o)[1] = *(int4*)&tile[cr][nc+8];
}

// ---------- covariance: covXY[s][b][j][i] += sum_n x_s[n,i]*y[n,j]  (stored transposed [j][i])
//            covXX[s-1][b][j][i] += sum_n x_s[n,i]*x_s[n,j]  (s>0; symmetric) ----------
__global__ __launch_bounds__(256) void k_cov(const short* __restrict__ xt,
                                             float* __restrict__ covXY, float* __restrict__ covXX){
  int ks = blockIdx.x, rb = blockIdx.y, sb = blockIdx.z;
  int s = sb >> 1, b = sb & 1;
  int t = threadIdx.x, l = t & 63, w = t >> 6;
  __shared__ short Xs[256][40], Ys[256][40];
  f32x4 axy[16], axx[16];
  #pragma unroll
  for(int i=0;i<16;++i){ axy[i]=(f32x4){0.f,0.f,0.f,0.f}; axx[i]=(f32x4){0.f,0.f,0.f,0.f}; }
  const short* ytg = xt + ((size_t)b*256)*16384;
  const short* xtg = xt + ((size_t)(s*2+b)*256)*16384;
  for(int kk=0; kk<32; ++kk){
    int nk = ks*1024 + kk*32;
    __syncthreads();
    {
      const int4* sy = (const int4*)(ytg + (size_t)t*16384 + nk);
      int4* dy = (int4*)&Ys[t][0];
      dy[0]=sy[0]; dy[1]=sy[1]; dy[2]=sy[2]; dy[3]=sy[3];
      if(s){
        const int4* sx = (const int4*)(xtg + (size_t)t*16384 + nk);
        int4* dx = (int4*)&Xs[t][0];
        dx[0]=sx[0]; dx[1]=sx[1]; dx[2]=sx[2]; dx[3]=sx[3];
      }
    }
    __syncthreads();
    const short (*As)[40] = s ? Xs : Ys;
    bf16x8 a = *(const bf16x8*)&As[rb*64 + 16*w + (l&15)][8*(l>>4)];
    #pragma unroll
    for(int nt=0; nt<16; ++nt){
      bf16x8 by = *(const bf16x8*)&Ys[nt*16 + (l&15)][8*(l>>4)];
      axy[nt] = MFMA16(a, by, axy[nt]);
      if(s){
        bf16x8 bx = *(const bf16x8*)&Xs[nt*16 + (l&15)][8*(l>>4)];
        axx[nt] = MFMA16(a, bx, axx[nt]);
      }
    }
  }
  float* cxy = covXY + (size_t)(s*2+b)*65536;
  #pragma unroll
  for(int nt=0; nt<16; ++nt)
    #pragma unroll
    for(int r=0;r<4;++r){
      int i = rb*64 + 16*w + 4*(l>>4) + r;   // A row (x channel)
      int j = nt*16 + (l&15);                // B col (y channel)
      atomicAdd(&cxy[(size_t)j*256 + i], axy[nt][r]);
    }
  if(s){
    float* cxx = covXX + (size_t)((s-1)*2+b)*65536;
    #pragma unroll
    for(int nt=0; nt<16; ++nt)
      #pragma unroll
      for(int r=0;r<4;++r){
        int i = rb*64 + 16*w + 4*(l>>4) + r;
        int j = nt*16 + (l&15);
        atomicAdd(&cxx[(size_t)j*256 + i], axx[nt][r]);
      }
  }
}

// ---------- helpers for 32x256 and 32x32 MFMA products in k_attn ----------
__device__ inline void mm_32x256(const short (*wA)[264], const short* __restrict__ covbf,
                                 short (*tmp)[264], int t){
  int l = t & 63, w = t >> 6;
  int mt = w >> 1, ntb = (w & 1)*8;
  f32x4 acc[8];
  #pragma unroll
  for(int i=0;i<8;++i) acc[i] = (f32x4){0.f,0.f,0.f,0.f};
  #pragma unroll
  for(int kk=0; kk<8; ++kk){
    bf16x8 a = *(const bf16x8*)&wA[16*mt + (l&15)][kk*32 + 8*(l>>4)];
    #pragma unroll
    for(int n=0; n<8; ++n){
      int j = (ntb+n)*16 + (l&15);
      bf16x8 bb = *(const bf16x8*)&covbf[(size_t)j*256 + kk*32 + 8*(l>>4)];
      acc[n] = MFMA16(a, bb, acc[n]);
    }
  }
  #pragma unroll
  for(int n=0;n<8;++n)
    #pragma unroll
    for(int r=0;r<4;++r)
      tmp[16*mt + 4*(l>>4) + r][(ntb+n)*16 + (l&15)] = f2bf(acc[n][r]);
}
__device__ inline void mm_32x32(const short (*A)[264], const short (*Bw)[264], float (*M)[33], int t){
  int l = t & 63, w = t >> 6;
  int mt = w >> 1, nt = w & 1;
  f32x4 acc = (f32x4){0.f,0.f,0.f,0.f};
  #pragma unroll
  for(int kk=0; kk<8; ++kk){
    bf16x8 a = *(const bf16x8*)&A[16*mt + (l&15)][kk*32 + 8*(l>>4)];
    bf16x8 b = *(const bf16x8*)&Bw[16*nt + (l&15)][kk*32 + 8*(l>>4)];
    acc = MFMA16(a, b, acc);
  }
  #pragma unroll
  for(int r=0;r<4;++r)
    M[16*mt + 4*(l>>4) + r][16*nt + (l&15)] = acc[r];
}

// ---------- attention matrices: G = Wk_h * Cov_xy * Wq_h^T, norms from Cxx/Cyy diag, softmax -> A ----------
__global__ __launch_bounds__(256) void k_attn(
    const float* __restrict__ Wq, const float* __restrict__ Wkm, const float* __restrict__ Wk2,
    const float* __restrict__ Wk4, const float* __restrict__ Wk8,
    const float* __restrict__ rsm, const float* __restrict__ rs2, const float* __restrict__ rs4,
    const short* __restrict__ covB, float* __restrict__ Aout){
  int h = blockIdx.x, b = blockIdx.y, br = blockIdx.z;
  int t = threadIdx.x;
  __shared__ short wk[32][264], wq[32][264], tmp[32][264];
  __shared__ float Ml[32][33];
  __shared__ float nrm[64];
  const float* Wk = (br==0)? Wkm : (br==1)? Wk2 : (br==2)? Wk4 : Wk8;
  {
    int d = t >> 3, c0 = (t & 7)*32;
    const float* pk = Wk + (size_t)(h*32+d)*256 + c0;
    const float* pq = Wq + (size_t)(h*32+d)*256 + c0;
    #pragma unroll
    for(int i=0;i<32;i+=8){
      float4 a1 = *(const float4*)(pk+i), a2 = *(const float4*)(pk+i+4);
      store8bf(&wk[d][c0+i], a1, a2);
      float4 b1 = *(const float4*)(pq+i), b2 = *(const float4*)(pq+i+4);
      store8bf(&wq[d][c0+i], b1, b2);
    }
  }
  __syncthreads();
  const short* cxy = covB + (size_t)(br*2+b)*65536;
  const short* cxx = (br==0)? cxy : covB + (size_t)(8 + (br-1)*2 + b)*65536;
  const short* cyy = covB + (size_t)b*65536;
  // k norms^2
  mm_32x256(wk, cxx, tmp, t); __syncthreads();
  mm_32x32(tmp, wk, Ml, t);   __syncthreads();
  if(t < 32) nrm[t] = Ml[t][t];
  __syncthreads();
  // q norms^2
  mm_32x256(wq, cyy, tmp, t); __syncthreads();
  mm_32x32(tmp, wq, Ml, t);   __syncthreads();
  if(t < 32) nrm[32+t] = Ml[t][t];
  __syncthreads();
  // G
  mm_32x256(wk, cxy, tmp, t); __syncthreads();
  mm_32x32(tmp, wq, Ml, t);   __syncthreads();
  if(t < 32){
    int d = t;
    const float* rs = (br==0)? rsm : (br==1)? rs2 : rs4;  // br==3 uses rescale4 (faithful to source)
    float rsv = rs[h];
    float invk = 1.f / fmaxf(sqrtf(fmaxf(nrm[d], 0.f)), 1e-12f);
    float lg[32]; float mx = -1e30f;
    #pragma unroll
    for(int e=0;e<32;++e){
      float invq = 1.f / fmaxf(sqrtf(fmaxf(nrm[32+e], 0.f)), 1e-12f);
      float v = Ml[d][e] * invk * invq * rsv;
      lg[e] = v; mx = fmaxf(mx, v);
    }
    float sum = 0.f;
    #pragma unroll
    for(int e=0;e<32;++e){ lg[e] = expf(lg[e]-mx); sum += lg[e]; }
    float inv = 1.f/sum;
    float* Ao = Aout + ((size_t)((br*2+b)*8 + h))*1024 + d*32;
    #pragma unroll
    for(int e=0;e<32;++e) Ao[e] = lg[e]*inv;
  }
}

// ---------- fold: Qf[br][b] = (Wproj ⊙head A) * Wv_br   (256x256 bf16 each) ----------
__global__ __launch_bounds__(256) void k_qfold(const float* __restrict__ Wproj, const float* __restrict__ Ain,
                                               const short* __restrict__ wvT, short* __restrict__ qf){
  int cg = blockIdx.x, b = blockIdx.y, br = blockIdx.z;
  int t = threadIdx.x;
  __shared__ float Al[8*1036];
  __shared__ short pl[32][264];
  const float* Ag = Ain + (size_t)((br*2+b)*8)*1024;
  for(int i=t; i<8192; i+=256){
    int hh = i >> 10, dd = (i >> 5) & 31, ee = i & 31;
    Al[hh*1036 + dd*32 + ee] = Ag[i];
  }
  __syncthreads();
  {
    int c = cg*32 + (t >> 3), h = t & 7;
    const float* wpr = Wproj + (size_t)c*256 + h*32;
    float wp[32];
    #pragma unroll
    for(int i=0;i<32;i+=4){
      float4 v = *(const float4*)(wpr+i);
      wp[i]=v.x; wp[i+1]=v.y; wp[i+2]=v.z; wp[i+3]=v.w;
    }
    float pv[32];
    #pragma unroll
    for(int e=0;e<32;++e) pv[e]=0.f;
    const float* Ah = Al + h*1036;
    #pragma unroll
    for(int d=0; d<32; ++d){
      float wpd = wp[d];
      #pragma unroll
      for(int e=0;e<32;e+=4){
        float4 av = *(const float4*)&Ah[d*32+e];
        pv[e]   += wpd*av.x; pv[e+1] += wpd*av.y;
        pv[e+2] += wpd*av.z; pv[e+3] += wpd*av.w;
      }
    }
    #pragma unroll
    for(int e=0;e<32;++e) pl[t>>3][h*32+e] = f2bf(pv[e]);
  }
  __syncthreads();
  {
    int l = t & 63, w = t >> 6, mt = w >> 1, ntb = (w & 1)*8;
    const short* wvt = wvT + (size_t)br*65536;
    f32x4 acc[8];
    #pragma unroll
    for(int i=0;i<8;++i) acc[i] = (f32x4){0.f,0.f,0.f,0.f};
    #pragma unroll
    for(int kk=0; kk<8; ++kk){
      bf16x8 a = *(const bf16x8*)&pl[16*mt + (l&15)][kk*32 + 8*(l>>4)];
      #pragma unroll
      for(int n=0;n<8;++n){
        int arow = (ntb+n)*16 + (l&15);
        bf16x8 bb = *(const bf16x8*)&wvt[(size_t)arow*256 + kk*32 + 8*(l>>4)];
        acc[n] = MFMA16(a, bb, acc[n]);
      }
    }
    short* qfp = qf + (size_t)(br*2+b)*65536;
    #pragma unroll
    for(int n=0;n<8;++n)
      #pragma unroll
      for(int r=0;r<4;++r){
        int row = cg*32 + 16*mt + 4*(l>>4) + r;
        int col = (ntb+n)*16 + (l&15);
        qfp[(size_t)row*256 + col] = f2bf(acc[n][r]);
      }
  }
}

// ---------- vm = y @ Wvm^T  (bf16 out) ----------
__global__ __launch_bounds__(256) void k_vm(const float* __restrict__ y, const short* __restrict__ wB,
                                            short* __restrict__ vm){
  int t = threadIdx.x;
  size_t m0 = (size_t)blockIdx.x*64;
  __shared__ short at[64][264];
  {
    int r = t & 63, c0 = (t >> 6)*64;
    const float* p = y + (m0+r)*256 + c0;
    #pragma unroll
    for(int i=0;i<64;i+=8){
      float4 a = *(const float4*)(p+i), b = *(const float4*)(p+i+4);
      store8bf(&at[r][c0+i], a, b);
    }
  }
  __syncthreads();
  int l = t & 63, w = t >> 6;
  f32x4 acc[16];
  #pragma unroll
  for(int i=0;i<16;++i) acc[i] = (f32x4){0.f,0.f,0.f,0.f};
  #pragma unroll
  for(int kk=0; kk<8; ++kk){
    bf16x8 a = *(const bf16x8*)&at[16*w + (l&15)][kk*32 + 8*(l>>4)];
    #pragma unroll
    for(int nt=0; nt<16; ++nt){
      bf16x8 bb = *(const bf16x8*)&wB[(size_t)(nt*16 + (l&15))*256 + kk*32 + 8*(l>>4)];
      acc[nt] = MFMA16(a, bb, acc[nt]);
    }
  }
  #pragma unroll
  for(int nt=0; nt<16; ++nt)
    #pragma unroll
    for(int r=0;r<4;++r){
      size_t row = m0 + 16*w + 4*(l>>4) + r;
      int col = nt*16 + (l&15);
      vm[row*256 + col] = f2bf(acc[nt][r]);
    }
}

// ---------- depthwise 3x3 conv (NHWC), optional exact GELU ----------
__global__ __launch_bounds__(256) void k_conv(const short* __restrict__ in, const float* __restrict__ w9,
                                              short* __restrict__ out, int do_gelu){
  int tid = blockIdx.x*256 + threadIdx.x;
  int cg = tid & 31; int pix = tid >> 5;
  int x = pix & 127, yy = (pix >> 7) & 127, b = pix >> 14;
  int c0 = cg*8;
  float acc[8];
  #pragma unroll
  for(int i=0;i<8;++i) acc[i]=0.f;
  #pragma unroll
  for(int ky=0; ky<3; ++ky){
    int sy = yy + ky - 1;
    if(sy < 0 || sy > 127) continue;
    #pragma unroll
    for(int kx=0; kx<3; ++kx){
      int sx = x + kx - 1;
      if(sx < 0 || sx > 127) continue;
      const short* p = in + ((size_t)(((b<<7)+sy)<<7) + sx)*256 + c0;
      union{ int4 q; short s[8]; } u;
      u.q = *(const int4*)p;
      #pragma unroll
      for(int cc=0;cc<8;++cc)
        acc[cc] += bf2f(u.s[cc]) * w9[(c0+cc)*9 + ky*3 + kx];
    }
  }
  if(do_gelu){
    #pragma unroll
    for(int cc=0;cc<8;++cc)
      acc[cc] = 0.5f*acc[cc]*(1.f + erff(acc[cc]*0.70710678118654752f));
  }
  union{ int4 q; short s[8]; } o;
  #pragma unroll
  for(int cc=0;cc<8;++cc) o.s[cc] = f2bf(acc[cc]);
  *(int4*)(out + (size_t)pix*256 + c0) = o.q;
}

// ---------- final: out = sum_br x_br @ Qf[br][b]^T + bproj + pos ----------
__global__ __launch_bounds__(256) void k_final(const float* __restrict__ y, const float* __restrict__ x2,
                                               const float* __restrict__ x4, const float* __restrict__ x8,
                                               const short* __restrict__ qf, const float* __restrict__ bproj,
                                               const short* __restrict__ pos, float* __restrict__ out){
  int t = threadIdx.x;
  size_t m0 = (size_t)blockIdx.x*64;
  int b = (int)(m0 >> 14);
  __shared__ short at[64][264];
  int l = t & 63, w = t >> 6;
  f32x4 acc[16];
  #pragma unroll
  for(int i=0;i<16;++i) acc[i] = (f32x4){0.f,0.f,0.f,0.f};
  const float* srcs[4] = {y, x2, x4, x8};
  #pragma unroll 1
  for(int br=0; br<4; ++br){
    __syncthreads();
    {
      int r = t & 63, c0 = (t >> 6)*64;
      const float* p = srcs[br] + (m0+r)*256 + c0;
      #pragma unroll
      for(int i=0;i<64;i+=8){
        float4 a = *(const float4*)(p+i), bb = *(const float4*)(p+i+4);
        store8bf(&at[r][c0+i], a, bb);
      }
    }
    __syncthreads();
    const short* qb = qf + (size_t)(br*2+b)*65536;
    #pragma unroll
    for(int kk=0; kk<8; ++kk){
      bf16x8 a = *(const bf16x8*)&at[16*w + (l&15)][kk*32 + 8*(l>>4)];
      #pragma unroll
      for(int nt=0; nt<16; ++nt){
        bf16x8 bb = *(const bf16x8*)&qb[(size_t)(nt*16 + (l&15))*256 + kk*32 + 8*(l>>4)];
        acc[nt] = MFMA16(a, bb, acc[nt]);
      }
    }
  }
  #pragma unroll
  for(int nt=0; nt<16; ++nt)
    #pragma unroll
    for(int r=0;r<4;++r){
      size_t row = m0 + 16*w + 4*(l>>4) + r;
      int col = nt*16 + (l&15);
      out[row*256 + col] = acc[nt][r] + bproj[col] + bf2f(pos[row*256 + col]);
    }
}

extern "C" void kernel_launch(void* const* d_in, const int* in_sizes, int n_in,
                              void* d_out, int out_size, void* d_ws, size_t ws_size,
                              hipStream_t stream){
  (void)in_sizes; (void)n_in; (void)out_size; (void)ws_size;
  const float* x2   = (const float*)d_in[0];
  const float* x4   = (const float*)d_in[1];
  const float* x8   = (const float*)d_in[2];
  const float* y    = (const float*)d_in[3];
  const float* Wq   = (const float*)d_in[4];
  const float* Wkm  = (const float*)d_in[5];
  const float* Wvm  = (const float*)d_in[6];
  const float* Wk2  = (const float*)d_in[7];
  const float* Wv2  = (const float*)d_in[8];
  const float* Wk4  = (const float*)d_in[9];
  const float* Wv4  = (const float*)d_in[10];
  const float* Wk8  = (const float*)d_in[11];
  const float* Wv8  = (const float*)d_in[12];
  const float* rsm  = (const float*)d_in[13];
  const float* rs2  = (const float*)d_in[14];
  const float* rs4  = (const float*)d_in[15];
  const float* Wproj= (const float*)d_in[17];
  const float* bproj= (const float*)d_in[18];
  const float* Wp1  = (const float*)d_in[19];
  const float* Wp2  = (const float*)d_in[20];
  float* out = (float*)d_out;

  char* ws = (char*)d_ws;
  // XT region: 4*2*256*16384 bf16 = 67,108,864 B.  After k_cov it is dead and
  // is reused for POS [0,16.78M), GBUF [16.78M,33.55M), VM [33.55M,50.33M).
  short* XT   = (short*)(ws + 0);
  short* POS  = (short*)(ws + 0);
  short* GBUF = (short*)(ws + 16777216);
  short* VM   = (short*)(ws + 33554432);
  float* covF = (float*)(ws + 67108864);            // 14 * 65536 f32 = 3,670,016 B
  short* covB = (short*)(ws + 70778880);            // 14 * 65536 bf16 = 1,835,008 B
  float* Aout = (float*)(ws + 72613888);            // 4*2*8*1024 f32 = 262,144 B
  short* QF   = (short*)(ws + 72876032);            // 8 * 65536 bf16 = 1,048,576 B
  short* WvmB = (short*)(ws + 73924608);            // 65536 bf16
  short* WvT  = (short*)(ws + 74055680);            // 4 * 65536 bf16
  // total ws use: 74,580,? ~ 71.2 MB

  hipMemsetAsync(covF, 0, 3670016, stream);
  k_cvt      <<<256, 256, 0, stream>>>(Wvm, WvmB, 65536);
  k_wvt      <<<1024, 256, 0, stream>>>(Wvm, Wv2, Wv4, Wv8, WvT);
  k_transpose<<<dim3(256,4,8), 256, 0, stream>>>(x2, x4, x8, y, XT);
  k_cov      <<<dim3(16,4,8), 256, 0, stream>>>(XT, covF, covF + 8*65536);
  k_cvt      <<<3584, 256, 0, stream>>>(covF, covB, 917504);
  k_attn     <<<dim3(8,2,4), 256, 0, stream>>>(Wq, Wkm, Wk2, Wk4, Wk8, rsm, rs2, rs4, covB, Aout);
  k_qfold    <<<dim3(8,2,4), 256, 0, stream>>>(Wproj, Aout, WvT, QF);
  k_vm       <<<512, 256, 0, stream>>>(y, WvmB, VM);
  k_conv     <<<4096, 256, 0, stream>>>(VM, Wp1, GBUF, 1);
  k_conv     <<<4096, 256, 0, stream>>>(GBUF, Wp2, POS, 0);
  k_final    <<<512, 256, 0, stream>>>(y, x2, x4, x8, QF, bproj, POS, out);
}

// Round 2
// 559.148 us; speedup vs baseline: 1.4276x; 1.4276x over previous
//
#include <hip/hip_runtime.h>
#include <hip/hip_bf16.h>
#include <math.h>

// Problem constants: B=2, H=W=128, C=256, HEADS=8, D=32, N=16384, M=B*N=32768
typedef short bf16x8 __attribute__((ext_vector_type(8)));
typedef float f32x4 __attribute__((ext_vector_type(4)));

#define MFMA16(a,b,c) __builtin_amdgcn_mfma_f32_16x16x32_bf16(a,b,c,0,0,0)

__device__ inline short f2bf(float f){
  union{ __hip_bfloat16 h; short s; } u;
  u.h = __float2bfloat16(f);
  return u.s;
}
__device__ inline float bf2f(short s){
  uint32_t u = ((uint32_t)(uint16_t)s) << 16;
  return __builtin_bit_cast(float, u);
}
__device__ inline void store8bf(short* dst, float4 a, float4 b){
  union{ short s[8]; int4 q; } u;
  u.s[0]=f2bf(a.x); u.s[1]=f2bf(a.y); u.s[2]=f2bf(a.z); u.s[3]=f2bf(a.w);
  u.s[4]=f2bf(b.x); u.s[5]=f2bf(b.y); u.s[6]=f2bf(b.z); u.s[7]=f2bf(b.w);
  *(int4*)dst = u.q;
}

// ---------- generic f32 -> bf16 convert ----------
__global__ __launch_bounds__(256) void k_cvt(const float* __restrict__ src, short* __restrict__ dst, int n){
  int i = blockIdx.x*256 + threadIdx.x;
  if(i < n) dst[i] = f2bf(src[i]);
}

// ---------- transpose-convert the 4 Wv matrices: WvT[br][a][j] = Wv_br[j][a] ----------
__global__ __launch_bounds__(256) void k_wvt(const float* __restrict__ wm, const float* __restrict__ w2,
                                             const float* __restrict__ w4, const float* __restrict__ w8,
                                             short* __restrict__ wvT){
  int t = blockIdx.x*256 + threadIdx.x;      // 4*65536 total
  int br = t >> 16; int rem = t & 65535; int a = rem >> 8, j = rem & 255;
  const float* w = (br==0)? wm : (br==1)? w2 : (br==2)? w4 : w8;
  wvT[t] = f2bf(w[j*256 + a]);
}

// ---------- swizzled LDS helpers for cov tiles (row stride 40 shorts = 80 B) ----------
__device__ inline void cov_ldsWrite8(short* base, int row, int w, const float* v){
  union{ short s[8]; int4 q; } u;
  #pragma unroll
  for(int i=0;i<8;++i) u.s[i] = f2bf(v[i]);
  int byte = row*80 + w*16;
  byte ^= ((row>>3)&7) << 4;
  *(int4*)((char*)base + byte) = u.q;
}
__device__ inline bf16x8 cov_ldsRead8(const short* base, int row, int colS){
  int byte = row*80 + colS*2;
  byte ^= ((row>>3)&7) << 4;
  return *(const bf16x8*)((const char*)base + byte);
}

// ---------- gram jobs: C_j = U^T V (256x256), direct from f32 inputs ----------
// jobs (j = blockIdx.z>>1, b = blockIdx.z&1):
//  0:(y,y)->slot b   1:(y,x2)->2+b   2:(y,x4)->4+b   3:(y,x8)->6+b
//  4:(x2,x2)->8+b    5:(x4,x4)->10+b 6:(x8,x8)->12+b
// stored cov[arow][bcol] at slot*65536 + arow*256+bcol  (arow = U channel = y-ch for cross)
__global__ __launch_bounds__(256,2) void k_cov(const float* __restrict__ x2, const float* __restrict__ x4,
                                               const float* __restrict__ x8, const float* __restrict__ y,
                                               float* __restrict__ covF){
  int ks = blockIdx.x;     // 0..31 : n-chunk of 512
  int rh = blockIdx.y;     // 0..1  : output row half
  int jb = blockIdx.z;     // 0..13
  int j = jb >> 1, b = jb & 1;
  int t = threadIdx.x, l = t & 63, w = t >> 6;
  __shared__ short Bs[256*40];
  __shared__ short As[128*40];
  const float *U, *V; int slot, sym;
  if(j==0){U=y;  V=y;  slot=b;    sym=1;}
  else if(j==1){U=y;  V=x2; slot=2+b;  sym=0;}
  else if(j==2){U=y;  V=x4; slot=4+b;  sym=0;}
  else if(j==3){U=y;  V=x8; slot=6+b;  sym=0;}
  else if(j==4){U=x2; V=x2; slot=8+b;  sym=1;}
  else if(j==5){U=x4; V=x4; slot=10+b; sym=1;}
  else        {U=x8; V=x8; slot=12+b; sym=1;}
  const float* Ug = U + (size_t)b*16384*256;
  const float* Vg = V + (size_t)b*16384*256;

  f32x4 acc[2][16];
  #pragma unroll
  for(int i=0;i<2;++i)
    #pragma unroll
    for(int n2=0;n2<16;++n2) acc[i][n2] = (f32x4){0.f,0.f,0.f,0.f};

  for(int it=0; it<16; ++it){
    int n0 = ks*512 + it*32;
    __syncthreads();
    // ---- stage V tile [32 n][256 c] -> Bs[c][nk] (coalesced wave-per-row loads) ----
    {
      float v0x[8], v0y[8], v1x[8], v1y[8];
      #pragma unroll
      for(int rr=0;rr<8;++rr){
        const float* p = Vg + (size_t)(n0 + w*8 + rr)*256 + 2*l;
        float2 a = *(const float2*)p;
        float2 c = *(const float2*)(p + 128);
        v0x[rr]=a.x; v0y[rr]=a.y; v1x[rr]=c.x; v1y[rr]=c.y;
      }
      cov_ldsWrite8(Bs, 2*l,     w, v0x);
      cov_ldsWrite8(Bs, 2*l+1,   w, v0y);
      cov_ldsWrite8(Bs, 128+2*l, w, v1x);
      cov_ldsWrite8(Bs, 129+2*l, w, v1y);
      if(!sym){
        float ax[8], ay[8];
        #pragma unroll
        for(int rr=0;rr<8;++rr){
          const float* q = Ug + (size_t)(n0 + w*8 + rr)*256 + rh*128 + 2*l;
          float2 a = *(const float2*)q;
          ax[rr]=a.x; ay[rr]=a.y;
        }
        cov_ldsWrite8(As, 2*l,   w, ax);
        cov_ldsWrite8(As, 2*l+1, w, ay);
      }
    }
    __syncthreads();
    // ---- MFMA: wave w owns A-local rows [w*32, w*32+32), all 256 B cols ----
    const short* Ab = sym ? (Bs + rh*5120) : As;   // rh*128 rows * 40 shorts
    bf16x8 afr[2];
    #pragma unroll
    for(int rt=0; rt<2; ++rt)
      afr[rt] = cov_ldsRead8(Ab, w*32 + rt*16 + (l&15), 8*(l>>4));
    #pragma unroll
    for(int nt=0; nt<16; ++nt){
      bf16x8 bfr = cov_ldsRead8(Bs, nt*16 + (l&15), 8*(l>>4));
      acc[0][nt] = MFMA16(afr[0], bfr, acc[0][nt]);
      acc[1][nt] = MFMA16(afr[1], bfr, acc[1][nt]);
    }
  }
  float* cov = covF + (size_t)slot*65536;
  #pragma unroll
  for(int rt=0;rt<2;++rt)
    #pragma unroll
    for(int nt=0;nt<16;++nt)
      #pragma unroll
      for(int r=0;r<4;++r){
        int row = rh*128 + w*32 + rt*16 + 4*(l>>4) + r;
        int col = nt*16 + (l&15);
        atomicAdd(&cov[(size_t)row*256 + col], acc[rt][nt][r]);
      }
}

// ---------- helpers for 32x256 and 32x32 MFMA products in k_attn ----------
__device__ inline void mm_32x256(const short (*wA)[264], const short* __restrict__ covbf,
                                 short (*tmp)[264], int t){
  int l = t & 63, w = t >> 6;
  int mt = w >> 1, ntb = (w & 1)*8;
  f32x4 acc[8];
  #pragma unroll
  for(int i=0;i<8;++i) acc[i] = (f32x4){0.f,0.f,0.f,0.f};
  #pragma unroll
  for(int kk=0; kk<8; ++kk){
    bf16x8 a = *(const bf16x8*)&wA[16*mt + (l&15)][kk*32 + 8*(l>>4)];
    #pragma unroll
    for(int n=0; n<8; ++n){
      int j = (ntb+n)*16 + (l&15);
      bf16x8 bb = *(const bf16x8*)&covbf[(size_t)j*256 + kk*32 + 8*(l>>4)];
      acc[n] = MFMA16(a, bb, acc[n]);
    }
  }
  #pragma unroll
  for(int n=0;n<8;++n)
    #pragma unroll
    for(int r=0;r<4;++r)
      tmp[16*mt + 4*(l>>4) + r][(ntb+n)*16 + (l&15)] = f2bf(acc[n][r]);
}
__device__ inline void mm_32x32(const short (*A)[264], const short (*Bw)[264], float (*M)[33], int t){
  int l = t & 63, w = t >> 6;
  int mt = w >> 1, nt = w & 1;
  f32x4 acc = (f32x4){0.f,0.f,0.f,0.f};
  #pragma unroll
  for(int kk=0; kk<8; ++kk){
    bf16x8 a = *(const bf16x8*)&A[16*mt + (l&15)][kk*32 + 8*(l>>4)];
    bf16x8 b = *(const bf16x8*)&Bw[16*nt + (l&15)][kk*32 + 8*(l>>4)];
    acc = MFMA16(a, b, acc);
  }
  #pragma unroll
  for(int r=0;r<4;++r)
    M[16*mt + 4*(l>>4) + r][16*nt + (l&15)] = acc[r];
}

// ---------- attention matrices: G = Wk_h * Cov_xy * Wq_h^T, norms from Cxx/Cyy diag, softmax -> A ----------
__global__ __launch_bounds__(256) void k_attn(
    const float* __restrict__ Wq, const float* __restrict__ Wkm, const float* __restrict__ Wk2,
    const float* __restrict__ Wk4, const float* __restrict__ Wk8,
    const float* __restrict__ rsm, const float* __restrict__ rs2, const float* __restrict__ rs4,
    const short* __restrict__ covB, float* __restrict__ Aout){
  int h = blockIdx.x, b = blockIdx.y, br = blockIdx.z;
  int t = threadIdx.x;
  __shared__ short wk[32][264], wq[32][264], tmp[32][264];
  __shared__ float Ml[32][33];
  __shared__ float nrm[64];
  const float* Wk = (br==0)? Wkm : (br==1)? Wk2 : (br==2)? Wk4 : Wk8;
  {
    int d = t >> 3, c0 = (t & 7)*32;
    const float* pk = Wk + (size_t)(h*32+d)*256 + c0;
    const float* pq = Wq + (size_t)(h*32+d)*256 + c0;
    #pragma unroll
    for(int i=0;i<32;i+=8){
      float4 a1 = *(const float4*)(pk+i), a2 = *(const float4*)(pk+i+4);
      store8bf(&wk[d][c0+i], a1, a2);
      float4 b1 = *(const float4*)(pq+i), b2 = *(const float4*)(pq+i+4);
      store8bf(&wq[d][c0+i], b1, b2);
    }
  }
  __syncthreads();
  const short* cxy = covB + (size_t)(br*2+b)*65536;
  const short* cxx = (br==0)? cxy : covB + (size_t)(8 + (br-1)*2 + b)*65536;
  const short* cyy = covB + (size_t)b*65536;
  // k norms^2
  mm_32x256(wk, cxx, tmp, t); __syncthreads();
  mm_32x32(tmp, wk, Ml, t);   __syncthreads();
  if(t < 32) nrm[t] = Ml[t][t];
  __syncthreads();
  // q norms^2
  mm_32x256(wq, cyy, tmp, t); __syncthreads();
  mm_32x32(tmp, wq, Ml, t);   __syncthreads();
  if(t < 32) nrm[32+t] = Ml[t][t];
  __syncthreads();
  // G
  mm_32x256(wk, cxy, tmp, t); __syncthreads();
  mm_32x32(tmp, wq, Ml, t);   __syncthreads();
  if(t < 32){
    int d = t;
    const float* rs = (br==0)? rsm : (br==1)? rs2 : rs4;  // br==3 uses rescale4 (faithful to source)
    float rsv = rs[h];
    float invk = 1.f / fmaxf(sqrtf(fmaxf(nrm[d], 0.f)), 1e-12f);
    float lg[32]; float mx = -1e30f;
    #pragma unroll
    for(int e=0;e<32;++e){
      float invq = 1.f / fmaxf(sqrtf(fmaxf(nrm[32+e], 0.f)), 1e-12f);
      float v = Ml[d][e] * invk * invq * rsv;
      lg[e] = v; mx = fmaxf(mx, v);
    }
    float sum = 0.f;
    #pragma unroll
    for(int e=0;e<32;++e){ lg[e] = expf(lg[e]-mx); sum += lg[e]; }
    float inv = 1.f/sum;
    float* Ao = Aout + ((size_t)((br*2+b)*8 + h))*1024 + d*32;
    #pragma unroll
    for(int e=0;e<32;++e) Ao[e] = lg[e]*inv;
  }
}

// ---------- fold: Qf[br][b] = (Wproj ⊙head A) * Wv_br   (256x256 bf16 each) ----------
__global__ __launch_bounds__(256) void k_qfold(const float* __restrict__ Wproj, const float* __restrict__ Ain,
                                               const short* __restrict__ wvT, short* __restrict__ qf){
  int cg = blockIdx.x, b = blockIdx.y, br = blockIdx.z;
  int t = threadIdx.x;
  __shared__ float Al[8*1036];
  __shared__ short pl[32][264];
  const float* Ag = Ain + (size_t)((br*2+b)*8)*1024;
  for(int i=t; i<8192; i+=256){
    int hh = i >> 10, dd = (i >> 5) & 31, ee = i & 31;
    Al[hh*1036 + dd*32 + ee] = Ag[i];
  }
  __syncthreads();
  {
    int c = cg*32 + (t >> 3), h = t & 7;
    const float* wpr = Wproj + (size_t)c*256 + h*32;
    float wp[32];
    #pragma unroll
    for(int i=0;i<32;i+=4){
      float4 v = *(const float4*)(wpr+i);
      wp[i]=v.x; wp[i+1]=v.y; wp[i+2]=v.z; wp[i+3]=v.w;
    }
    float pv[32];
    #pragma unroll
    for(int e=0;e<32;++e) pv[e]=0.f;
    const float* Ah = Al + h*1036;
    #pragma unroll
    for(int d=0; d<32; ++d){
      float wpd = wp[d];
      #pragma unroll
      for(int e=0;e<32;e+=4){
        float4 av = *(const float4*)&Ah[d*32+e];
        pv[e]   += wpd*av.x; pv[e+1] += wpd*av.y;
        pv[e+2] += wpd*av.z; pv[e+3] += wpd*av.w;
      }
    }
    #pragma unroll
    for(int e=0;e<32;++e) pl[t>>3][h*32+e] = f2bf(pv[e]);
  }
  __syncthreads();
  {
    int l = t & 63, w = t >> 6, mt = w >> 1, ntb = (w & 1)*8;
    const short* wvt = wvT + (size_t)br*65536;
    f32x4 acc[8];
    #pragma unroll
    for(int i=0;i<8;++i) acc[i] = (f32x4){0.f,0.f,0.f,0.f};
    #pragma unroll
    for(int kk=0; kk<8; ++kk){
      bf16x8 a = *(const bf16x8*)&pl[16*mt + (l&15)][kk*32 + 8*(l>>4)];
      #pragma unroll
      for(int n=0;n<8;++n){
        int arow = (ntb+n)*16 + (l&15);
        bf16x8 bb = *(const bf16x8*)&wvt[(size_t)arow*256 + kk*32 + 8*(l>>4)];
        acc[n] = MFMA16(a, bb, acc[n]);
      }
    }
    short* qfp = qf + (size_t)(br*2+b)*65536;
    #pragma unroll
    for(int n=0;n<8;++n)
      #pragma unroll
      for(int r=0;r<4;++r){
        int row = cg*32 + 16*mt + 4*(l>>4) + r;
        int col = (ntb+n)*16 + (l&15);
        qfp[(size_t)row*256 + col] = f2bf(acc[n][r]);
      }
  }
}

// ---------- swizzled LDS helpers for [64][256] bf16 A-tiles ----------
__device__ inline void at_write4(short* base, int row, int l, float4 v){
  union{ short s[4]; int2 q; } u;
  u.s[0]=f2bf(v.x); u.s[1]=f2bf(v.y); u.s[2]=f2bf(v.z); u.s[3]=f2bf(v.w);
  int byte = row*512 + 8*l;
  byte ^= ((row&7)<<4);
  *(int2*)((char*)base + byte) = u.q;
}
__device__ inline bf16x8 at_read8(const short* base, int row, int kk, int q){
  int byte = row*512 + kk*64 + q*16;
  byte ^= ((row&7)<<4);
  return *(const bf16x8*)((const char*)base + byte);
}

// ---------- vm = y @ Wvm^T  (bf16 out) ----------
__global__ __launch_bounds__(256,2) void k_vm(const float* __restrict__ y, const short* __restrict__ wB,
                                              short* __restrict__ vm){
  int t = threadIdx.x, l = t & 63, w = t >> 6;
  size_t m0 = (size_t)blockIdx.x*64;
  __shared__ short at[64*256];
  #pragma unroll
  for(int rr=0; rr<16; ++rr){
    int row = w*16 + rr;
    float4 v = *(const float4*)(y + (m0+row)*256 + 4*l);
    at_write4(at, row, l, v);
  }
  __syncthreads();
  f32x4 acc[4][4];
  #pragma unroll
  for(int i=0;i<4;++i)
    #pragma unroll
    for(int n2=0;n2<4;++n2) acc[i][n2] = (f32x4){0.f,0.f,0.f,0.f};
  #pragma unroll
  for(int kk=0; kk<8; ++kk){
    bf16x8 a[4];
    #pragma unroll
    for(int rt=0;rt<4;++rt) a[rt] = at_read8(at, rt*16 + (l&15), kk, l>>4);
    #pragma unroll
    for(int nt=0;nt<4;++nt){
      int bc = (w*4+nt)*16 + (l&15);
      bf16x8 bb = *(const bf16x8*)&wB[(size_t)bc*256 + kk*32 + 8*(l>>4)];
      #pragma unroll
      for(int rt=0;rt<4;++rt) acc[rt][nt] = MFMA16(a[rt], bb, acc[rt][nt]);
    }
  }
  #pragma unroll
  for(int rt=0;rt<4;++rt)
    #pragma unroll
    for(int nt=0;nt<4;++nt)
      #pragma unroll
      for(int r=0;r<4;++r){
        size_t row = m0 + rt*16 + 4*(l>>4) + r;
        int col = (w*4+nt)*16 + (l&15);
        vm[row*256 + col] = f2bf(acc[rt][nt][r]);
      }
}

// ---------- depthwise 3x3 conv (NHWC), optional exact GELU ----------
__global__ __launch_bounds__(256) void k_conv(const short* __restrict__ in, const float* __restrict__ w9,
                                              short* __restrict__ out, int do_gelu){
  int tid = blockIdx.x*256 + threadIdx.x;
  int cg = tid & 31; int pix = tid >> 5;
  int x = pix & 127, yy = (pix >> 7) & 127, b = pix >> 14;
  int c0 = cg*8;
  float acc[8];
  #pragma unroll
  for(int i=0;i<8;++i) acc[i]=0.f;
  #pragma unroll
  for(int ky=0; ky<3; ++ky){
    int sy = yy + ky - 1;
    if(sy < 0 || sy > 127) continue;
    #pragma unroll
    for(int kx=0; kx<3; ++kx){
      int sx = x + kx - 1;
      if(sx < 0 || sx > 127) continue;
      const short* p = in + ((size_t)(((b<<7)+sy)<<7) + sx)*256 + c0;
      union{ int4 q; short s[8]; } u;
      u.q = *(const int4*)p;
      #pragma unroll
      for(int cc=0;cc<8;++cc)
        acc[cc] += bf2f(u.s[cc]) * w9[(c0+cc)*9 + ky*3 + kx];
    }
  }
  if(do_gelu){
    #pragma unroll
    for(int cc=0;cc<8;++cc)
      acc[cc] = 0.5f*acc[cc]*(1.f + erff(acc[cc]*0.70710678118654752f));
  }
  union{ int4 q; short s[8]; } o;
  #pragma unroll
  for(int cc=0;cc<8;++cc) o.s[cc] = f2bf(acc[cc]);
  *(int4*)(out + (size_t)pix*256 + c0) = o.q;
}

// ---------- final: out = sum_br x_br @ Qf[br][b]^T + bproj + pos ----------
__global__ __launch_bounds__(256,2) void k_final(const float* __restrict__ y, const float* __restrict__ x2,
                                                 const float* __restrict__ x4, const float* __restrict__ x8,
                                                 const short* __restrict__ qf, const float* __restrict__ bproj,
                                                 const short* __restrict__ pos, float* __restrict__ out){
  int t = threadIdx.x, l = t & 63, w = t >> 6;
  size_t m0 = (size_t)blockIdx.x*64;
  int b = (int)(m0 >> 14);
  __shared__ short at[64*256];
  f32x4 acc[4][4];
  #pragma unroll
  for(int i=0;i<4;++i)
    #pragma unroll
    for(int n2=0;n2<4;++n2) acc[i][n2] = (f32x4){0.f,0.f,0.f,0.f};
  const float* srcs[4] = {y, x2, x4, x8};
  #pragma unroll 1
  for(int br=0; br<4; ++br){
    __syncthreads();
    #pragma unroll
    for(int rr=0; rr<16; ++rr){
      int row = w*16 + rr;
      float4 v = *(const float4*)(srcs[br] + (m0+row)*256 + 4*l);
      at_write4(at, row, l, v);
    }
    __syncthreads();
    const short* qb = qf + (size_t)(br*2+b)*65536;
    #pragma unroll
    for(int kk=0; kk<8; ++kk){
      bf16x8 a[4];
      #pragma unroll
      for(int rt=0;rt<4;++rt) a[rt] = at_read8(at, rt*16 + (l&15), kk, l>>4);
      #pragma unroll
      for(int nt=0;nt<4;++nt){
        int bc = (w*4+nt)*16 + (l&15);
        bf16x8 bb = *(const bf16x8*)&qb[(size_t)bc*256 + kk*32 + 8*(l>>4)];
        #pragma unroll
        for(int rt=0;rt<4;++rt) acc[rt][nt] = MFMA16(a[rt], bb, acc[rt][nt]);
      }
    }
  }
  #pragma unroll
  for(int rt=0;rt<4;++rt)
    #pragma unroll
    for(int nt=0;nt<4;++nt)
      #pragma unroll
      for(int r=0;r<4;++r){
        size_t row = m0 + rt*16 + 4*(l>>4) + r;
        int col = (w*4+nt)*16 + (l&15);
        out[row*256 + col] = acc[rt][nt][r] + bproj[col] + bf2f(pos[row*256 + col]);
      }
}

extern "C" void kernel_launch(void* const* d_in, const int* in_sizes, int n_in,
                              void* d_out, int out_size, void* d_ws, size_t ws_size,
                              hipStream_t stream){
  (void)in_sizes; (void)n_in; (void)out_size; (void)ws_size;
  const float* x2   = (const float*)d_in[0];
  const float* x4   = (const float*)d_in[1];
  const float* x8   = (const float*)d_in[2];
  const float* y    = (const float*)d_in[3];
  const float* Wq   = (const float*)d_in[4];
  const float* Wkm  = (const float*)d_in[5];
  const float* Wvm  = (const float*)d_in[6];
  const float* Wk2  = (const float*)d_in[7];
  const float* Wv2  = (const float*)d_in[8];
  const float* Wk4  = (const float*)d_in[9];
  const float* Wv4  = (const float*)d_in[10];
  const float* Wk8  = (const float*)d_in[11];
  const float* Wv8  = (const float*)d_in[12];
  const float* rsm  = (const float*)d_in[13];
  const float* rs2  = (const float*)d_in[14];
  const float* rs4  = (const float*)d_in[15];
  const float* Wproj= (const float*)d_in[17];
  const float* bproj= (const float*)d_in[18];
  const float* Wp1  = (const float*)d_in[19];
  const float* Wp2  = (const float*)d_in[20];
  float* out = (float*)d_out;

  char* ws = (char*)d_ws;
  short* VM   = (short*)(ws + 0);                   // 16,777,216 B
  short* GBUF = (short*)(ws + 16777216);            // 16,777,216 B
  short* POS  = (short*)(ws + 33554432);            // 16,777,216 B
  float* covF = (float*)(ws + 50331648);            // 14*65536*4 = 3,670,016 B
  short* covB = (short*)(ws + 54001664);            // 14*65536*2 = 1,835,008 B
  float* Aout = (float*)(ws + 55836672);            // 262,144 B
  short* QF   = (short*)(ws + 56098816);            // 1,048,576 B
  short* WvmB = (short*)(ws + 57147392);            // 131,072 B
  short* WvT  = (short*)(ws + 57278464);            // 524,288 B  (end ~57.8 MB)

  hipMemsetAsync(covF, 0, 3670016, stream);
  k_cvt  <<<256, 256, 0, stream>>>(Wvm, WvmB, 65536);
  k_wvt  <<<1024, 256, 0, stream>>>(Wvm, Wv2, Wv4, Wv8, WvT);
  k_cov  <<<dim3(32,2,14), 256, 0, stream>>>(x2, x4, x8, y, covF);
  k_cvt  <<<3584, 256, 0, stream>>>(covF, covB, 917504);
  k_attn <<<dim3(8,2,4), 256, 0, stream>>>(Wq, Wkm, Wk2, Wk4, Wk8, rsm, rs2, rs4, covB, Aout);
  k_qfold<<<dim3(8,2,4), 256, 0, stream>>>(Wproj, Aout, WvT, QF);
  k_vm   <<<512, 256, 0, stream>>>(y, WvmB, VM);
  k_conv <<<4096, 256, 0, stream>>>(VM, Wp1, GBUF, 1);
  k_conv <<<4096, 256, 0, stream>>>(GBUF, Wp2, POS, 0);
  k_final<<<512, 256, 0, stream>>>(y, x2, x4, x8, QF, bproj, POS, out);
}